// Round 1
// 2231.598 us; speedup vs baseline: 1.1290x; 1.1290x over previous
//
#include <hip/hip_runtime.h>
#include <stdint.h>

#define IN_F   20000
#define OUT_F  3000
#define BATCH  8192

// ---------------------------------------------------------------------------
// Kernel 1: transpose + f32->bf16 downcast.  x [BATCH, IN_F] f32 row-major
// -> xT [IN_F, BATCH] bf16 (raw ushort).  128(batch) x 64(col) LDS tile.
// Phase 1: float4 coalesced reads (256B/wave-row).  Phase 2: pack 2
// consecutive-batch bf16 into one u32 -> 256B contiguous wave stores.
// tile[128][65] padding: phase-2 reads tile[2bp][c] hit even banks only
// (2-way conflict = free per m136).
// ---------------------------------------------------------------------------
__global__ __launch_bounds__(256)
void k_transpose(const float* __restrict__ x, uint16_t* __restrict__ xT) {
    __shared__ float tile[128][65];     // 33.3 KB
    const int c0 = blockIdx.x * 64;     // column (IN_F) tile base
    const int b0 = blockIdx.y * 128;    // batch tile base
    const int tid = threadIdx.x;

    // Phase 1: 128 rows x 16 float4 = 2048 slots, 8 iters of 256 threads.
#pragma unroll
    for (int i = 0; i < 8; ++i) {
        int idx = tid + i * 256;
        int b = idx >> 4, cq = idx & 15;       // lanes consecutive in cq -> coalesced
        int cc = c0 + cq * 4;
        float4 v = make_float4(0.f, 0.f, 0.f, 0.f);
        if (cc < IN_F)                          // IN_F%4==0 so cc<IN_F => cc+3<IN_F
            v = *(const float4*)&x[(size_t)(b0 + b) * IN_F + cc];
        tile[b][cq * 4 + 0] = v.x;
        tile[b][cq * 4 + 1] = v.y;
        tile[b][cq * 4 + 2] = v.z;
        tile[b][cq * 4 + 3] = v.w;
    }
    __syncthreads();

    // Phase 2: 64 cols x 64 packed-u32 (=128 batch) = 4096 slots, 16 iters.
    // Per wave: one c, bp=0..63 -> 256B contiguous u32 store.
#pragma unroll
    for (int i = 0; i < 16; ++i) {
        int idx = tid + i * 256;
        int c = idx >> 6, bp = idx & 63;
        int cc = c0 + c;
        if (cc < IN_F) {
            uint32_t u0 = __float_as_uint(tile[2 * bp + 0][c]);
            uint32_t u1 = __float_as_uint(tile[2 * bp + 1][c]);
            // round-to-nearest-even bf16 (inputs finite)
            uint32_t r0 = (u0 + 0x7fffu + ((u0 >> 16) & 1u)) >> 16;
            uint32_t r1 = (u1 + 0x7fffu + ((u1 >> 16) & 1u)) >> 16;
            *(uint32_t*)&xT[(size_t)cc * BATCH + (b0 + 2 * bp)] = r0 | (r1 << 16);
        }
    }
}

// ---------------------------------------------------------------------------
// Kernel 2: CSR row_ptr[OUT_F+1] from sorted `rows` (row-major coalesced COO).
// ---------------------------------------------------------------------------
__global__ __launch_bounds__(256)
void k_row_ptr(const int* __restrict__ rows, int* __restrict__ row_ptr, int nnz) {
    int k = blockIdx.x * 256 + threadIdx.x;
    if (k >= nnz) return;
    int r  = rows[k];
    int rp = (k == 0) ? -1 : rows[k - 1];
    for (int q = rp + 1; q <= r; ++q) row_ptr[q] = k;
    if (k == nnz - 1) {
        for (int q = r + 1; q <= OUT_F; ++q) row_ptr[q] = nnz;
    }
}

// ---------------------------------------------------------------------------
// Kernel 3: SpMM.  Block = 128 threads = 16 rows x 8 lanes; each lane owns
// 16 consecutive batch elements (two 16B dwordx4 of bf16 per nnz).
// BT=128: halves cols/w re-streams vs BT=64, 2 independent loads per nnz.
// k-loop unrolled by 2 -> 4 concurrent xT loads per lane (latency hiding).
// Grid swizzle: blockIdx%8 -> XCD; each XCD walks its own batch tiles so the
// xT slice stays hot in its L2/L3 across the ~30x column reuse.
// ---------------------------------------------------------------------------
#define ROWS_PB 16
#define LANES   8
#define BT      128                                   // batch per block
#define NRG     ((OUT_F + ROWS_PB - 1) / ROWS_PB)     // 188 row groups
#define NTILES  (BATCH / BT)                          // 64 batch tiles
#define TPX     (NTILES / 8)                          // 8 tiles per XCD

#define BF_LO(u) __uint_as_float((u) << 16)
#define BF_HI(u) __uint_as_float((u) & 0xffff0000u)
#define FMA8(A, q, wv)                                              \
    A[0] = fmaf(wv, BF_LO((q).x), A[0]);                            \
    A[1] = fmaf(wv, BF_HI((q).x), A[1]);                            \
    A[2] = fmaf(wv, BF_LO((q).y), A[2]);                            \
    A[3] = fmaf(wv, BF_HI((q).y), A[3]);                            \
    A[4] = fmaf(wv, BF_LO((q).z), A[4]);                            \
    A[5] = fmaf(wv, BF_HI((q).z), A[5]);                            \
    A[6] = fmaf(wv, BF_LO((q).w), A[6]);                            \
    A[7] = fmaf(wv, BF_HI((q).w), A[7]);

__global__ __launch_bounds__(128)
void k_spmm(const uint16_t* __restrict__ xT, const float* __restrict__ w,
            const float* __restrict__ bias, const int* __restrict__ cols,
            const int* __restrict__ row_ptr, float* __restrict__ out) {
    const int i = blockIdx.x;
    const int xcd = i & 7;
    const int j = i >> 3;
    const int tile_local = j / NRG;             // 0..TPX-1, slow per XCD
    const int row_grp   = j - tile_local * NRG; // 0..NRG-1, fast per XCD
    const int tile = xcd + 8 * tile_local;      // 0..NTILES-1
    const int b0 = tile * BT;

    const int t = threadIdx.x;
    const int row_sub = t >> 3;     // 0..15
    const int lane8  = t & 7;       // 0..7
    const int r = row_grp * ROWS_PB + row_sub;
    if (r >= OUT_F) return;

    const int kbeg = row_ptr[r];
    const int kend = row_ptr[r + 1];

    // lane owns batch [b0 + lane8*16, +16)
    const uint16_t* xbase = xT + (size_t)(b0 + lane8 * 16);

    float acc[16];
#pragma unroll
    for (int e = 0; e < 16; ++e) acc[e] = 0.f;

    int k = kbeg;
    for (; k + 1 < kend; k += 2) {
        int   c0 = cols[k],   c1 = cols[k + 1];   // broadcast across 8 lanes
        float w0 = w[k],      w1 = w[k + 1];
        const uint16_t* a0 = xbase + ((size_t)c0 << 13);   // c*BATCH elems
        const uint16_t* a1 = xbase + ((size_t)c1 << 13);
        uint4 q0 = *(const uint4*)(a0);
        uint4 q1 = *(const uint4*)(a0 + 8);
        uint4 q2 = *(const uint4*)(a1);
        uint4 q3 = *(const uint4*)(a1 + 8);
        FMA8(acc,       q0, w0);
        FMA8((acc + 8), q1, w0);
        FMA8(acc,       q2, w1);
        FMA8((acc + 8), q3, w1);
    }
    if (k < kend) {
        int   c0 = cols[k];
        float w0 = w[k];
        const uint16_t* a0 = xbase + ((size_t)c0 << 13);
        uint4 q0 = *(const uint4*)(a0);
        uint4 q1 = *(const uint4*)(a0 + 8);
        FMA8(acc,       q0, w0);
        FMA8((acc + 8), q1, w0);
    }

    const float bv = bias[r];
    const int   bb = b0 + lane8 * 16;
#pragma unroll
    for (int e = 0; e < 16; ++e) {
        out[(size_t)(bb + e) * OUT_F + r] = acc[e] + bv;
    }
}

// ---------------------------------------------------------------------------
extern "C" void kernel_launch(void* const* d_in, const int* in_sizes, int n_in,
                              void* d_out, int out_size, void* d_ws, size_t ws_size,
                              hipStream_t stream) {
    const float* x    = (const float*)d_in[0];   // [BATCH, IN_F] f32
    const float* w    = (const float*)d_in[1];   // [NNZ] f32
    const float* bias = (const float*)d_in[2];   // [OUT_F] f32
    const int*   rows = (const int*)d_in[3];     // [NNZ] i32, sorted (row-major)
    const int*   cols = (const int*)d_in[4];     // [NNZ] i32
    float*       out  = (float*)d_out;           // [BATCH, OUT_F] f32
    const int    nnz  = in_sizes[1];

    // workspace layout: [0,16K) row_ptr (3001 ints); [16K, +327.68MB) xT bf16
    int*      row_ptr = (int*)d_ws;
    uint16_t* xT      = (uint16_t*)((char*)d_ws + 16384);

    dim3 gT((IN_F + 63) / 64, BATCH / 128);
    hipLaunchKernelGGL(k_transpose, gT, dim3(256), 0, stream, x, xT);
    hipLaunchKernelGGL(k_row_ptr, dim3((nnz + 255) / 256), dim3(256), 0, stream,
                       rows, row_ptr, nnz);
    hipLaunchKernelGGL(k_spmm, dim3(8 * TPX * NRG), dim3(128), 0, stream,
                       xT, w, bias, cols, row_ptr, out);
}

// Round 2
// 2164.112 us; speedup vs baseline: 1.1642x; 1.0312x over previous
//
#include <hip/hip_runtime.h>
#include <stdint.h>

#define IN_F   20000
#define OUT_F  3000
#define BATCH  8192

#define CHUNK     2048                 // batch chunk: xT chunk = 20000*2048*2 = 81.9 MB -> MALL-resident
#define NCHUNKS   (BATCH / CHUNK)      // 4

// ---------------------------------------------------------------------------
// Kernel 1: transpose + f32->bf16 downcast of ONE batch chunk.
// x [BATCH, IN_F] f32 row-major -> xT [IN_F, BATCH] bf16 (raw ushort).
// 128(batch) x 64(col) tile, bf16 LDS (17.4 KB -> 8 blocks/CU, 32 waves/CU).
// Phase 1: float4 coalesced reads, convert to bf16, uint2 LDS writes
//   (row stride 68 u16 = 136 B, 8B-aligned).
// Phase 2: 2 u16 LDS reads (4-way bank alias, 1.58x - fine), packed u32
//   stores -> 256B contiguous per wave per column.
// ---------------------------------------------------------------------------
__global__ __launch_bounds__(256)
void k_transpose(const float* __restrict__ x, uint16_t* __restrict__ xT,
                 int b_base) {
    __shared__ uint16_t tile[128][68];
    const int c0 = blockIdx.x * 64;                 // column (IN_F) tile base
    const int b0 = b_base + blockIdx.y * 128;       // batch tile base
    const int tid = threadIdx.x;

    // Phase 1: 128 rows x 16 float4 = 2048 slots, 8 iters of 256 threads.
#pragma unroll
    for (int i = 0; i < 8; ++i) {
        int idx = tid + i * 256;
        int b = idx >> 4, cq = idx & 15;            // lanes consecutive in cq
        int cc = c0 + cq * 4;
        float4 v = make_float4(0.f, 0.f, 0.f, 0.f);
        if (cc < IN_F)                              // IN_F%4==0: cc<IN_F => cc+3<IN_F
            v = *(const float4*)&x[(size_t)(b0 + b) * IN_F + cc];
        uint32_t u0 = __float_as_uint(v.x), u1 = __float_as_uint(v.y);
        uint32_t u2 = __float_as_uint(v.z), u3 = __float_as_uint(v.w);
        // round-to-nearest-even bf16 (inputs finite)
        uint32_t r0 = (u0 + 0x7fffu + ((u0 >> 16) & 1u)) >> 16;
        uint32_t r1 = (u1 + 0x7fffu + ((u1 >> 16) & 1u)) >> 16;
        uint32_t r2 = (u2 + 0x7fffu + ((u2 >> 16) & 1u)) >> 16;
        uint32_t r3 = (u3 + 0x7fffu + ((u3 >> 16) & 1u)) >> 16;
        uint2 pk = make_uint2(r0 | (r1 << 16), r2 | (r3 << 16));
        *(uint2*)&tile[b][cq * 4] = pk;             // 136*b + 8*cq: 8B aligned
    }
    __syncthreads();

    // Phase 2: 64 cols x 64 batch-pairs = 4096 slots, 16 iters.
    // Wave: one c, bp=0..63 -> 256B contiguous u32 store.
#pragma unroll
    for (int i = 0; i < 16; ++i) {
        int idx = tid + i * 256;
        int c = idx >> 6, bp = idx & 63;
        int cc = c0 + c;
        if (cc < IN_F) {
            uint32_t lo = tile[2 * bp + 0][c];
            uint32_t hi = tile[2 * bp + 1][c];
            *(uint32_t*)&xT[(size_t)cc * BATCH + (b0 + 2 * bp)] = lo | (hi << 16);
        }
    }
}

// ---------------------------------------------------------------------------
// Kernel 2: CSR row_ptr[OUT_F+1] from sorted `rows` (row-major coalesced COO).
// ---------------------------------------------------------------------------
__global__ __launch_bounds__(256)
void k_row_ptr(const int* __restrict__ rows, int* __restrict__ row_ptr, int nnz) {
    int k = blockIdx.x * 256 + threadIdx.x;
    if (k >= nnz) return;
    int r  = rows[k];
    int rp = (k == 0) ? -1 : rows[k - 1];
    for (int q = rp + 1; q <= r; ++q) row_ptr[q] = k;
    if (k == nnz - 1) {
        for (int q = r + 1; q <= OUT_F; ++q) row_ptr[q] = nnz;
    }
}

// ---------------------------------------------------------------------------
// Kernel 3: SpMM over ONE batch chunk (xT chunk is MALL/L2-resident).
// Block = 128 threads = 16 rows x 8 lanes; lane owns 8 batch elems (one
// 16B dwordx4 of bf16 per nnz).  BT=64: per-XCD tile slice = 2.56 MB < 4MB L2.
// k-loop unrolled x4 with software-prefetched cols/w: 4 independent xT loads
// in flight per lane (VGPR ~48, pinned <=64 via launch_bounds -> 32 waves/CU).
// Grid swizzle: blockIdx%8 -> XCD; each XCD owns its batch tiles.
// ---------------------------------------------------------------------------
#define ROWS_PB 16
#define BT      64                                    // batch per block
#define NRG     ((OUT_F + ROWS_PB - 1) / ROWS_PB)     // 188 row groups
#define NTILES  (CHUNK / BT)                          // 32 batch tiles per chunk
#define TPX     (NTILES / 8)                          // 4 tiles per XCD

#define BF_LO(u) __uint_as_float((u) << 16)
#define BF_HI(u) __uint_as_float((u) & 0xffff0000u)
#define FMA8(A, q, wv)                                              \
    A[0] = fmaf(wv, BF_LO((q).x), A[0]);                            \
    A[1] = fmaf(wv, BF_HI((q).x), A[1]);                            \
    A[2] = fmaf(wv, BF_LO((q).y), A[2]);                            \
    A[3] = fmaf(wv, BF_HI((q).y), A[3]);                            \
    A[4] = fmaf(wv, BF_LO((q).z), A[4]);                            \
    A[5] = fmaf(wv, BF_HI((q).z), A[5]);                            \
    A[6] = fmaf(wv, BF_LO((q).w), A[6]);                            \
    A[7] = fmaf(wv, BF_HI((q).w), A[7]);

__global__ __launch_bounds__(128, 8)
void k_spmm(const uint16_t* __restrict__ xT, const float* __restrict__ w,
            const float* __restrict__ bias, const int* __restrict__ cols,
            const int* __restrict__ row_ptr, float* __restrict__ out,
            int b_base) {
    const int i = blockIdx.x;
    const int xcd = i & 7;
    const int j = i >> 3;
    const int tile_local = j / NRG;             // 0..TPX-1, slow per XCD
    const int row_grp   = j - tile_local * NRG; // 0..NRG-1, fast per XCD
    const int tile = xcd + 8 * tile_local;      // 0..NTILES-1
    const int b0 = b_base + tile * BT;

    const int t = threadIdx.x;
    const int row_sub = t >> 3;     // 0..15
    const int lane8  = t & 7;       // 0..7
    const int r = row_grp * ROWS_PB + row_sub;
    if (r >= OUT_F) return;

    const int kbeg = row_ptr[r];
    const int kend = row_ptr[r + 1];

    const uint16_t* xbase = xT + (size_t)(b0 + lane8 * 8);

    float acc[8];
#pragma unroll
    for (int e = 0; e < 8; ++e) acc[e] = 0.f;

    int k = kbeg;
    int   c0n = 0, c1n = 0, c2n = 0, c3n = 0;
    float w0n = 0.f, w1n = 0.f, w2n = 0.f, w3n = 0.f;
    if (k + 3 < kend) {
        c0n = cols[k];     c1n = cols[k + 1];
        c2n = cols[k + 2]; c3n = cols[k + 3];
        w0n = w[k];     w1n = w[k + 1];
        w2n = w[k + 2]; w3n = w[k + 3];
    }
    while (k + 3 < kend) {
        const int   c0 = c0n, c1 = c1n, c2 = c2n, c3 = c3n;
        const float w0 = w0n, w1 = w1n, w2 = w2n, w3 = w3n;
        // 4 independent 16B loads in flight
        uint4 q0 = *(const uint4*)(xbase + ((size_t)c0 << 13));
        uint4 q1 = *(const uint4*)(xbase + ((size_t)c1 << 13));
        uint4 q2 = *(const uint4*)(xbase + ((size_t)c2 << 13));
        uint4 q3 = *(const uint4*)(xbase + ((size_t)c3 << 13));
        k += 4;
        if (k + 3 < kend) {            // prefetch next group's cols/w under the loads
            c0n = cols[k];     c1n = cols[k + 1];
            c2n = cols[k + 2]; c3n = cols[k + 3];
            w0n = w[k];     w1n = w[k + 1];
            w2n = w[k + 2]; w3n = w[k + 3];
        }
        FMA8(acc, q0, w0);
        FMA8(acc, q1, w1);
        FMA8(acc, q2, w2);
        FMA8(acc, q3, w3);
    }
    for (; k < kend; ++k) {
        int   c  = cols[k];
        float wv = w[k];
        uint4 q = *(const uint4*)(xbase + ((size_t)c << 13));
        FMA8(acc, q, wv);
    }

    const float bv = bias[r];
    const int   bb = b0 + lane8 * 8;
#pragma unroll
    for (int e = 0; e < 8; ++e) {
        out[(size_t)(bb + e) * OUT_F + r] = acc[e] + bv;
    }
}

// ---------------------------------------------------------------------------
extern "C" void kernel_launch(void* const* d_in, const int* in_sizes, int n_in,
                              void* d_out, int out_size, void* d_ws, size_t ws_size,
                              hipStream_t stream) {
    const float* x    = (const float*)d_in[0];   // [BATCH, IN_F] f32
    const float* w    = (const float*)d_in[1];   // [NNZ] f32
    const float* bias = (const float*)d_in[2];   // [OUT_F] f32
    const int*   rows = (const int*)d_in[3];     // [NNZ] i32, sorted (row-major)
    const int*   cols = (const int*)d_in[4];     // [NNZ] i32
    float*       out  = (float*)d_out;           // [BATCH, OUT_F] f32
    const int    nnz  = in_sizes[1];

    // workspace layout: [0,16K) row_ptr (3001 ints); [16K, +327.68MB) xT bf16
    int*      row_ptr = (int*)d_ws;
    uint16_t* xT      = (uint16_t*)((char*)d_ws + 16384);

    hipLaunchKernelGGL(k_row_ptr, dim3((nnz + 255) / 256), dim3(256), 0, stream,
                       rows, row_ptr, nnz);

    // Interleave per-chunk transpose + spmm: the 82 MB xT chunk written by
    // k_transpose is MALL-resident when its k_spmm consumes it.
    dim3 gT((IN_F + 63) / 64, CHUNK / 128);
    for (int ch = 0; ch < NCHUNKS; ++ch) {
        int b_base = ch * CHUNK;
        hipLaunchKernelGGL(k_transpose, gT, dim3(256), 0, stream, x, xT, b_base);
        hipLaunchKernelGGL(k_spmm, dim3(8 * TPX * NRG), dim3(128), 0, stream,
                           xT, w, bias, cols, row_ptr, out, b_base);
    }
}

// Round 4
// 1979.932 us; speedup vs baseline: 1.2725x; 1.0930x over previous
//
#include <hip/hip_runtime.h>
#include <stdint.h>

#define IN_F   20000
#define OUT_F  3000
#define BATCH  8192

#define CHUNK     4096                 // xT chunk = 20000*4096*2 = 164 MB -> L3-resident
#define NCHUNKS   (BATCH / CHUNK)      // 2

// ---------------------------------------------------------------------------
// Kernel 1: transpose + f32->bf16 downcast of ONE batch chunk, c-walking.
// x [BATCH, IN_F] f32 -> xT [IN_F, BATCH] bf16 (raw ushort).
// Block owns a 128-batch tile and walks TW=8 consecutive 64-col subtiles, so
// each x row is read as a 2 KB SEQUENTIAL stream (fixes the 256 B/row DRAM
// crumbs that held round-1/2 transpose at ~1.1 TB/s).
// LDS 17.4 KB -> 8 blocks/CU (32 waves).
// ---------------------------------------------------------------------------
#define TW 8
__global__ __launch_bounds__(256)
void k_transpose(const float* __restrict__ x, uint16_t* __restrict__ xT,
                 int b_base) {
    __shared__ uint16_t tile[128][68];
    const int b0  = b_base + blockIdx.y * 128;
    const int tid = threadIdx.x;
    const int cbase = blockIdx.x * (64 * TW);

    for (int s = 0; s < TW; ++s) {
        const int c0 = cbase + s * 64;      // block-uniform: no divergent break
        if (c0 >= IN_F) break;
        if (s) __syncthreads();             // LDS reuse across subtiles

        // Phase 1: 128 rows x 16 float4, 8 iters of 256 threads.
#pragma unroll
        for (int i = 0; i < 8; ++i) {
            int idx = tid + i * 256;
            int b = idx >> 4, cq = idx & 15;     // lanes consecutive in cq
            int cc = c0 + cq * 4;
            float4 v = make_float4(0.f, 0.f, 0.f, 0.f);
            if (cc < IN_F)                       // IN_F%4==0
                v = *(const float4*)&x[(size_t)(b0 + b) * IN_F + cc];
            uint32_t u0 = __float_as_uint(v.x), u1 = __float_as_uint(v.y);
            uint32_t u2 = __float_as_uint(v.z), u3 = __float_as_uint(v.w);
            // round-to-nearest-even bf16 (inputs finite)
            uint32_t r0 = (u0 + 0x7fffu + ((u0 >> 16) & 1u)) >> 16;
            uint32_t r1 = (u1 + 0x7fffu + ((u1 >> 16) & 1u)) >> 16;
            uint32_t r2 = (u2 + 0x7fffu + ((u2 >> 16) & 1u)) >> 16;
            uint32_t r3 = (u3 + 0x7fffu + ((u3 >> 16) & 1u)) >> 16;
            uint2 pk = make_uint2(r0 | (r1 << 16), r2 | (r3 << 16));
            *(uint2*)&tile[b][cq * 4] = pk;      // 136b+8cq: 8B aligned
        }
        __syncthreads();

        // Phase 2: 64 cols x 64 batch-pairs, u32 packed -> 256B/wave stores.
#pragma unroll
        for (int i = 0; i < 16; ++i) {
            int idx = tid + i * 256;
            int c = idx >> 6, bp = idx & 63;
            int cc = c0 + c;
            if (cc < IN_F) {
                uint32_t lo = tile[2 * bp + 0][c];
                uint32_t hi = tile[2 * bp + 1][c];
                *(uint32_t*)&xT[(size_t)cc * BATCH + (b0 + 2 * bp)] =
                    lo | (hi << 16);
            }
        }
    }
}

// ---------------------------------------------------------------------------
// Kernel 2: CSR row_ptr[OUT_F+1] from sorted `rows`.
// ---------------------------------------------------------------------------
__global__ __launch_bounds__(256)
void k_row_ptr(const int* __restrict__ rows, int* __restrict__ row_ptr, int nnz) {
    int k = blockIdx.x * 256 + threadIdx.x;
    if (k >= nnz) return;
    int r  = rows[k];
    int rp = (k == 0) ? -1 : rows[k - 1];
    for (int q = rp + 1; q <= r; ++q) row_ptr[q] = k;
    if (k == nnz - 1) {
        for (int q = r + 1; q <= OUT_F; ++q) row_ptr[q] = nnz;
    }
}

// ---------------------------------------------------------------------------
// Kernel 3: SpMM, ROW-PER-WAVE.  Block = 256 thr = 4 waves = 4 consecutive
// rows; each wave owns one row over a BT=512 batch tile: lane l holds batch
// [b0+8l, +8), so every nnz is ONE fully-coalesced 1 KB wave load.
// cols/w/row_ptr are wave-uniform -> scalar loads, zero per-lane address
// math in the k-loop.  Explicit 2-stage double buffer of 4 uint4 loads
// (VGPR ~52, capped 64 via launch_bounds -> 32 waves/CU) hides L3 latency.
// tile = blk&7: 8 batch tiles in flight -> xT working set 8x20 MB = 160 MB
// < 256 MB L3, so the ~30x cross-row column reuse is MALL-served.
// Epilogue: LDS [4][520] transpose -> 16B-packed out stores.
// ---------------------------------------------------------------------------
#define BT      512
#define NTILES  (CHUNK / BT)            // 8 tiles per chunk
#define NRG     (OUT_F / 4)             // 750 row groups of 4

#define BF_LO(u) __uint_as_float((u) << 16)
#define BF_HI(u) __uint_as_float((u) & 0xffff0000u)
#define FMA8(A, q, wv)                                              \
    A[0] = fmaf(wv, BF_LO((q).x), A[0]);                            \
    A[1] = fmaf(wv, BF_HI((q).x), A[1]);                            \
    A[2] = fmaf(wv, BF_LO((q).y), A[2]);                            \
    A[3] = fmaf(wv, BF_HI((q).y), A[3]);                            \
    A[4] = fmaf(wv, BF_LO((q).z), A[4]);                            \
    A[5] = fmaf(wv, BF_HI((q).z), A[5]);                            \
    A[6] = fmaf(wv, BF_LO((q).w), A[6]);                            \
    A[7] = fmaf(wv, BF_HI((q).w), A[7]);

__global__ __launch_bounds__(256, 8)
void k_spmm(const uint16_t* __restrict__ xT, const float* __restrict__ w,
            const float* __restrict__ bias, const int* __restrict__ cols,
            const int* __restrict__ row_ptr, float* __restrict__ out,
            int b_base) {
    __shared__ float ot[4][520];        // 8.3 KB: [wave][batch-local], pad 8

    const int blk  = blockIdx.x;
    const int tile = blk & 7;                   // heuristically the XCD
    const int rg   = blk >> 3;                  // 0..749
    const int b0   = b_base + tile * BT;

    const int wv = __builtin_amdgcn_readfirstlane(threadIdx.x >> 6);
    const int l  = threadIdx.x & 63;
    const int r  = rg * 4 + wv;                 // < 3000 always

    const int kbeg = row_ptr[r];
    const int kend = row_ptr[r + 1];

    const uint16_t* xb = xT + ((size_t)b0 + l * 8);

    float acc[8];
#pragma unroll
    for (int e = 0; e < 8; ++e) acc[e] = 0.f;

    int k = kbeg;
    uint4 qa0 = make_uint4(0, 0, 0, 0), qa1 = qa0, qa2 = qa0, qa3 = qa0;
    if (k + 4 <= kend) {
        qa0 = *(const uint4*)(xb + ((size_t)cols[k + 0] << 13));
        qa1 = *(const uint4*)(xb + ((size_t)cols[k + 1] << 13));
        qa2 = *(const uint4*)(xb + ((size_t)cols[k + 2] << 13));
        qa3 = *(const uint4*)(xb + ((size_t)cols[k + 3] << 13));
    }
    while (k + 8 <= kend) {
        float w0 = w[k + 0], w1 = w[k + 1], w2 = w[k + 2], w3 = w[k + 3];
        // issue next 4 loads before consuming current 4
        uint4 qb0 = *(const uint4*)(xb + ((size_t)cols[k + 4] << 13));
        uint4 qb1 = *(const uint4*)(xb + ((size_t)cols[k + 5] << 13));
        uint4 qb2 = *(const uint4*)(xb + ((size_t)cols[k + 6] << 13));
        uint4 qb3 = *(const uint4*)(xb + ((size_t)cols[k + 7] << 13));
        FMA8(acc, qa0, w0);
        FMA8(acc, qa1, w1);
        FMA8(acc, qa2, w2);
        FMA8(acc, qa3, w3);
        qa0 = qb0; qa1 = qb1; qa2 = qb2; qa3 = qb3;
        k += 4;
    }
    if (k + 4 <= kend) {                // drain buffered group
        float w0 = w[k + 0], w1 = w[k + 1], w2 = w[k + 2], w3 = w[k + 3];
        FMA8(acc, qa0, w0);
        FMA8(acc, qa1, w1);
        FMA8(acc, qa2, w2);
        FMA8(acc, qa3, w3);
        k += 4;
    }
    for (; k < kend; ++k) {
        float wvl = w[k];
        uint4 q = *(const uint4*)(xb + ((size_t)cols[k] << 13));
        FMA8(acc, q, wvl);
    }

    const float bv = bias[r];
#pragma unroll
    for (int e = 0; e < 8; ++e) acc[e] += bv;

    // Epilogue: stage [4 rows][512 b] in LDS, emit 16B stores (4 rows/b).
    *(float4*)&ot[wv][l * 8 + 0] = make_float4(acc[0], acc[1], acc[2], acc[3]);
    *(float4*)&ot[wv][l * 8 + 4] = make_float4(acc[4], acc[5], acc[6], acc[7]);
    __syncthreads();

    const int rb = rg * 4;
#pragma unroll
    for (int i = 0; i < 2; ++i) {
        int bb = threadIdx.x + i * 256;
        float4 o = make_float4(ot[0][bb], ot[1][bb], ot[2][bb], ot[3][bb]);
        *(float4*)&out[(size_t)(b0 + bb) * OUT_F + rb] = o;
    }
}

// ---------------------------------------------------------------------------
extern "C" void kernel_launch(void* const* d_in, const int* in_sizes, int n_in,
                              void* d_out, int out_size, void* d_ws, size_t ws_size,
                              hipStream_t stream) {
    const float* x    = (const float*)d_in[0];   // [BATCH, IN_F] f32
    const float* w    = (const float*)d_in[1];   // [NNZ] f32
    const float* bias = (const float*)d_in[2];   // [OUT_F] f32
    const int*   rows = (const int*)d_in[3];     // [NNZ] i32, sorted
    const int*   cols = (const int*)d_in[4];     // [NNZ] i32
    float*       out  = (float*)d_out;           // [BATCH, OUT_F] f32
    const int    nnz  = in_sizes[1];

    // workspace: [0,16K) row_ptr; [16K, +327.68MB) xT bf16
    int*      row_ptr = (int*)d_ws;
    uint16_t* xT      = (uint16_t*)((char*)d_ws + 16384);

    hipLaunchKernelGGL(k_row_ptr, dim3((nnz + 255) / 256), dim3(256), 0, stream,
                       rows, row_ptr, nnz);

    dim3 gT((IN_F + 64 * TW - 1) / (64 * TW), CHUNK / 128);   // (40, 32)
    for (int ch = 0; ch < NCHUNKS; ++ch) {
        int b_base = ch * CHUNK;
        hipLaunchKernelGGL(k_transpose, gT, dim3(256), 0, stream, x, xT, b_base);
        hipLaunchKernelGGL(k_spmm, dim3(NTILES * NRG), dim3(256), 0, stream,
                           xT, w, bias, cols, row_ptr, out, b_base);
    }
}